// Round 1
// baseline (1045.308 us; speedup 1.0000x reference)
//
#include <hip/hip_runtime.h>

// Problem constants (from reference): B=64, C=1, H=W=1024, KS=16, F=128, OUT=10
// L = 64*64 = 4096 patch locations, K = KS*KS = 256 elements per patch.
#define B_    64
#define F_    128
#define L_    4096
#define K_    256
#define OUT_  10
#define HW_   (1024 * 1024)   // per-image plane (C=1)
#define WIMG_ 1024            // image width

// ---------------------------------------------------------------------------
// Kernel A: one block per patch location l.
//   256 threads: tx = t&15 -> 4 batches each (b = tx*4..+3)
//                ty = t>>4 -> 8 filters each (f = ty*8..+7)
// Register-tiled 64x128x256 GEMM (per l), fused bias+ReLU+decoder contraction.
// Writes per-l partial decoder outputs to ws[b][l][o]  (64 x 4096 x 10 fp32).
// ---------------------------------------------------------------------------
__global__ __launch_bounds__(256, 2)
void lcn_main(const float* __restrict__ x, const float* __restrict__ wgt,
              const float* __restrict__ bias, const float* __restrict__ dec_w,
              float* __restrict__ ws) {
    const int l  = blockIdx.x;
    const int hb = l >> 6;          // H/KS = 64
    const int wb = l & 63;          // W/KS = 64
    const int t  = threadIdx.x;
    const int tx = t & 15;
    const int ty = t >> 4;
    const int b0 = tx * 4;
    const int f0 = ty * 8;

    // Patch base for batch b0: x[b, hb*16 + i, wb*16 + j]
    const float* xbase = x + (size_t)b0 * HW_ + (size_t)(hb * 16) * WIMG_ + wb * 16;
    // Weight base for filter f0 at location l: wgt[f, l, i, j]
    const float* wbase = wgt + (size_t)f0 * ((size_t)L_ * K_) + (size_t)l * K_;

    float acc[4][8];
    #pragma unroll
    for (int i = 0; i < 4; ++i)
        #pragma unroll
        for (int j = 0; j < 8; ++j) acc[i][j] = 0.f;

    // k = i*16 + j ; process in quads q (k = 4q), never crossing an image row.
    #pragma unroll 4
    for (int q = 0; q < 64; ++q) {
        const int xoff = (q >> 2) * WIMG_ + (q & 3) * 4;  // i*1024 + j
        float4 p[4];
        #pragma unroll
        for (int bi = 0; bi < 4; ++bi)
            p[bi] = *reinterpret_cast<const float4*>(xbase + (size_t)bi * HW_ + xoff);
        float4 w[8];
        #pragma unroll
        for (int fj = 0; fj < 8; ++fj)
            w[fj] = *reinterpret_cast<const float4*>(wbase + (size_t)fj * ((size_t)L_ * K_) + q * 4);
        #pragma unroll
        for (int bi = 0; bi < 4; ++bi)
            #pragma unroll
            for (int fj = 0; fj < 8; ++fj) {
                acc[bi][fj] = fmaf(p[bi].x, w[fj].x, acc[bi][fj]);
                acc[bi][fj] = fmaf(p[bi].y, w[fj].y, acc[bi][fj]);
                acc[bi][fj] = fmaf(p[bi].z, w[fj].z, acc[bi][fj]);
                acc[bi][fj] = fmaf(p[bi].w, w[fj].w, acc[bi][fj]);
            }
    }

    // Epilogue: bias + ReLU + decoder partial contraction over this thread's 8 f's.
    float part[4][OUT_];
    #pragma unroll
    for (int bi = 0; bi < 4; ++bi)
        #pragma unroll
        for (int o = 0; o < OUT_; ++o) part[bi][o] = 0.f;

    #pragma unroll
    for (int fj = 0; fj < 8; ++fj) {
        const int f = f0 + fj;
        const float bv = bias[(size_t)f * L_ + l];
        float yv[4];
        #pragma unroll
        for (int bi = 0; bi < 4; ++bi)
            yv[bi] = fmaxf(acc[bi][fj] + bv, 0.f);
        #pragma unroll
        for (int o = 0; o < OUT_; ++o) {
            const float dw = dec_w[(size_t)o * ((size_t)F_ * L_) + (size_t)f * L_ + l];
            #pragma unroll
            for (int bi = 0; bi < 4; ++bi)
                part[bi][o] = fmaf(yv[bi], dw, part[bi][o]);
        }
    }

    // Block reduction across the 16 f-groups (ty), deterministic.
    __shared__ float red[16][B_][OUT_];   // 40960 B
    #pragma unroll
    for (int bi = 0; bi < 4; ++bi)
        #pragma unroll
        for (int o = 0; o < OUT_; ++o)
            red[ty][b0 + bi][o] = part[bi][o];
    __syncthreads();

    for (int idx = t; idx < B_ * OUT_; idx += 256) {
        const int b = idx / OUT_;
        const int o = idx - b * OUT_;
        float s = 0.f;
        #pragma unroll
        for (int g = 0; g < 16; ++g) s += red[g][b][o];
        ws[(size_t)b * ((size_t)L_ * OUT_) + (size_t)l * OUT_ + o] = s;
    }
}

// ---------------------------------------------------------------------------
// Kernel B: reduce ws over l, add dec_b.  64 blocks (one per batch) x 640 thr.
// Thread j = lc*10 + o accumulates l = lc + 64*i  ->  coalesced reads.
// ---------------------------------------------------------------------------
__global__ __launch_bounds__(640)
void lcn_reduce(const float* __restrict__ ws, const float* __restrict__ dec_b,
                float* __restrict__ out) {
    const int b = blockIdx.x;
    const int j = threadIdx.x;            // 0..639
    const float* base = ws + (size_t)b * ((size_t)L_ * OUT_);

    float s = 0.f;
    #pragma unroll 8
    for (int i = 0; i < 64; ++i)
        s += base[j + i * (64 * OUT_)];

    __shared__ float lds[64 * OUT_];
    lds[j] = s;
    __syncthreads();

    if (j < OUT_) {
        float tot = dec_b[j];
        #pragma unroll
        for (int lc = 0; lc < 64; ++lc) tot += lds[lc * OUT_ + j];
        out[b * OUT_ + j] = tot;
    }
}

extern "C" void kernel_launch(void* const* d_in, const int* in_sizes, int n_in,
                              void* d_out, int out_size, void* d_ws, size_t ws_size,
                              hipStream_t stream) {
    const float* x     = (const float*)d_in[0];
    const float* wgt   = (const float*)d_in[1];
    const float* bias  = (const float*)d_in[2];
    const float* dec_w = (const float*)d_in[3];
    const float* dec_b = (const float*)d_in[4];
    float* out = (float*)d_out;
    float* wsf = (float*)d_ws;   // needs 64*4096*10*4 = 10.49 MB

    lcn_main<<<dim3(L_), dim3(256), 0, stream>>>(x, wgt, bias, dec_w, wsf);
    lcn_reduce<<<dim3(B_), dim3(640), 0, stream>>>(wsf, dec_b, out);
}

// Round 2
// 340.453 us; speedup vs baseline: 3.0703x; 3.0703x over previous
//
#include <hip/hip_runtime.h>

// Problem constants: B=64, C=1, H=W=1024, KS=16, F=128, OUT=10
// L = 4096 patch locations, K = 256 elements per patch.
#define B_    64
#define F_    128
#define L_    4096
#define K_    256
#define OUT_  10
#define HW_   (1024 * 1024)   // per-image plane (C=1)
#define WIMG_ 1024            // image width
#define CHUNK 32
#define NCHUNK (K_ / CHUNK)   // 8
#define XPAD  (CHUNK + 1)     // 33: x read banks spread (2-way, free)
#define WPAD  (F_ + 4)        // 132: w write banks spread, b128 reads conflict-free

// ---------------------------------------------------------------------------
// Kernel A: one block per patch location l. 256 threads = 4 waves.
// LDS double-buffered staging:
//   xs[b][k]   (pad 33)  <- coalesced-ish global loads (64B row segments)
//   wsm[k][f]  (pad 132) <- transposed store; k-contiguous 128B global loads
// Compute: thread (tx,ty) owns 4 batches x 8 filters; per k-step
//   4 ds_read_b32 (x, 2-way free) + 2 ds_read_b128 (w, broadcast) + 32 FMA.
// Epilogue: bias+ReLU+decoder partials, LDS tree reduce, ws[b][l][o].
// ---------------------------------------------------------------------------
__global__ __launch_bounds__(256, 3)
void lcn_main(const float* __restrict__ x, const float* __restrict__ wgt,
              const float* __restrict__ bias, const float* __restrict__ dec_w,
              float* __restrict__ ws) {
    const int l  = blockIdx.x;
    const int hb = l >> 6;          // H/KS = 64
    const int wb = l & 63;          // W/KS = 64
    const int t  = threadIdx.x;
    const int tx = t & 15;
    const int ty = t >> 4;
    const int b0 = tx * 4;
    const int f0 = ty * 8;

    __shared__ union {
        struct { float xs[B_][XPAD]; float wsm[CHUNK][WPAD]; } buf[2];
        float red[16][B_][OUT_];    // 40960 B, reused after main loop
    } sm;

    // Staging thread mapping
    const int sxb  = t >> 2;          // x: batch 0..63
    const int sxk0 = (t & 3) * 8;     // x: kk start (0,8,16,24)
    const int swf  = t >> 1;          // w: filter 0..127
    const int swk0 = (t & 1) * 16;    // w: kk start (0,16)

    const float* xb  = x + (size_t)sxb * HW_ + (size_t)(hb * 16) * WIMG_ + wb * 16;
    const float* wbf = wgt + ((size_t)swf * L_ + l) * K_;

    float4 xg[2], wg[4];

    auto LOADC = [&](int c) {
        const int k0 = c * CHUNK + sxk0;            // multiple of 8
        xg[0] = *reinterpret_cast<const float4*>(xb + (k0 >> 4) * WIMG_ + (k0 & 15));
        xg[1] = *reinterpret_cast<const float4*>(xb + ((k0 + 4) >> 4) * WIMG_ + ((k0 + 4) & 15));
        const float* wp = wbf + c * CHUNK + swk0;
        wg[0] = *reinterpret_cast<const float4*>(wp);
        wg[1] = *reinterpret_cast<const float4*>(wp + 4);
        wg[2] = *reinterpret_cast<const float4*>(wp + 8);
        wg[3] = *reinterpret_cast<const float4*>(wp + 12);
    };
    auto WRITEC = [&](int cur) {
        float* xs = &sm.buf[cur].xs[0][0];
        float* wm = &sm.buf[cur].wsm[0][0];
        #pragma unroll
        for (int e = 0; e < 8; ++e)
            xs[sxb * XPAD + sxk0 + e] = (&xg[0].x)[e];
        #pragma unroll
        for (int e = 0; e < 16; ++e)
            wm[(swk0 + e) * WPAD + swf] = (&wg[0].x)[e];
    };

    float acc[4][8];
    #pragma unroll
    for (int i = 0; i < 4; ++i)
        #pragma unroll
        for (int j = 0; j < 8; ++j) acc[i][j] = 0.f;

    // Prologue: fill buf0, issue loads for chunk 1
    LOADC(0);
    WRITEC(0);          // compiler inserts vmcnt wait before ds_writes
    LOADC(1);
    __syncthreads();

    int cur = 0;
    for (int c = 0; c < NCHUNK; ++c) {
        const float* xs = &sm.buf[cur].xs[0][0];
        const float* wm = &sm.buf[cur].wsm[0][0];
        #pragma unroll 4
        for (int kk = 0; kk < CHUNK; ++kk) {
            const float4 w0 = *reinterpret_cast<const float4*>(wm + kk * WPAD + f0);
            const float4 w1 = *reinterpret_cast<const float4*>(wm + kk * WPAD + f0 + 4);
            float xv[4];
            #pragma unroll
            for (int bi = 0; bi < 4; ++bi)
                xv[bi] = xs[(b0 + bi) * XPAD + kk];
            #pragma unroll
            for (int bi = 0; bi < 4; ++bi) {
                acc[bi][0] = fmaf(xv[bi], w0.x, acc[bi][0]);
                acc[bi][1] = fmaf(xv[bi], w0.y, acc[bi][1]);
                acc[bi][2] = fmaf(xv[bi], w0.z, acc[bi][2]);
                acc[bi][3] = fmaf(xv[bi], w0.w, acc[bi][3]);
                acc[bi][4] = fmaf(xv[bi], w1.x, acc[bi][4]);
                acc[bi][5] = fmaf(xv[bi], w1.y, acc[bi][5]);
                acc[bi][6] = fmaf(xv[bi], w1.z, acc[bi][6]);
                acc[bi][7] = fmaf(xv[bi], w1.w, acc[bi][7]);
            }
        }
        if (c + 1 < NCHUNK) {
            WRITEC(cur ^ 1);                 // chunk c+1 (regs -> LDS)
            if (c + 2 < NCHUNK) LOADC(c + 2);
        }
        __syncthreads();
        cur ^= 1;
    }

    // Epilogue: bias + ReLU + decoder partial contraction over this thread's 8 f's.
    float part[4][OUT_];
    #pragma unroll
    for (int bi = 0; bi < 4; ++bi)
        #pragma unroll
        for (int o = 0; o < OUT_; ++o) part[bi][o] = 0.f;

    #pragma unroll
    for (int fj = 0; fj < 8; ++fj) {
        const int f = f0 + fj;
        const float bv = bias[(size_t)f * L_ + l];
        float yv[4];
        #pragma unroll
        for (int bi = 0; bi < 4; ++bi)
            yv[bi] = fmaxf(acc[bi][fj] + bv, 0.f);
        #pragma unroll
        for (int o = 0; o < OUT_; ++o) {
            const float dw = dec_w[(size_t)o * ((size_t)F_ * L_) + (size_t)f * L_ + l];
            #pragma unroll
            for (int bi = 0; bi < 4; ++bi)
                part[bi][o] = fmaf(yv[bi], dw, part[bi][o]);
        }
    }

    // Block reduction across the 16 f-groups (tx dimension carries batches).
    // (last __syncthreads of the main loop already separates buf use from red)
    #pragma unroll
    for (int bi = 0; bi < 4; ++bi)
        #pragma unroll
        for (int o = 0; o < OUT_; ++o)
            sm.red[ty][b0 + bi][o] = part[bi][o];
    __syncthreads();

    for (int idx = t; idx < B_ * OUT_; idx += 256) {
        const int b = idx / OUT_;
        const int o = idx - b * OUT_;
        float s = 0.f;
        #pragma unroll
        for (int g = 0; g < 16; ++g) s += sm.red[g][b][o];
        ws[(size_t)b * ((size_t)L_ * OUT_) + (size_t)l * OUT_ + o] = s;
    }
}

// ---------------------------------------------------------------------------
// Kernel B: reduce ws over l, add dec_b.  64 blocks (one per batch) x 640 thr.
// ---------------------------------------------------------------------------
__global__ __launch_bounds__(640)
void lcn_reduce(const float* __restrict__ ws, const float* __restrict__ dec_b,
                float* __restrict__ out) {
    const int b = blockIdx.x;
    const int j = threadIdx.x;            // 0..639
    const float* base = ws + (size_t)b * ((size_t)L_ * OUT_);

    float s = 0.f;
    #pragma unroll 8
    for (int i = 0; i < 64; ++i)
        s += base[j + i * (64 * OUT_)];

    __shared__ float lds[64 * OUT_];
    lds[j] = s;
    __syncthreads();

    if (j < OUT_) {
        float tot = dec_b[j];
        #pragma unroll
        for (int lc = 0; lc < 64; ++lc) tot += lds[lc * OUT_ + j];
        out[b * OUT_ + j] = tot;
    }
}

extern "C" void kernel_launch(void* const* d_in, const int* in_sizes, int n_in,
                              void* d_out, int out_size, void* d_ws, size_t ws_size,
                              hipStream_t stream) {
    const float* x     = (const float*)d_in[0];
    const float* wgt   = (const float*)d_in[1];
    const float* bias  = (const float*)d_in[2];
    const float* dec_w = (const float*)d_in[3];
    const float* dec_b = (const float*)d_in[4];
    float* out = (float*)d_out;
    float* wsf = (float*)d_ws;   // 64*4096*10*4 = 10.49 MB

    lcn_main<<<dim3(L_), dim3(256), 0, stream>>>(x, wgt, bias, dec_w, wsf);
    lcn_reduce<<<dim3(B_), dim3(640), 0, stream>>>(wsf, dec_b, out);
}

// Round 3
// 274.135 us; speedup vs baseline: 3.8131x; 1.2419x over previous
//
#include <hip/hip_runtime.h>
#include <hip/hip_bf16.h>

// B=64, C=1, H=W=1024, KS=16, F=128, OUT=10, L=4096, K=256
#define B_    64
#define F_    128
#define L_    4096
#define K_    256
#define OUT_  10
#define HW_   (1024 * 1024)
#define WIMG_ 1024
#define CHUNK 64            // k per staged chunk (4 image rows)
#define NCHUNK 4

typedef __attribute__((ext_vector_type(8))) short bf16x8;   // MFMA A/B frag (8 bf16)
typedef __attribute__((ext_vector_type(4))) float f32x4;    // MFMA C/D frag

static __device__ __forceinline__ unsigned short f2bf(float f) {
    return __builtin_bit_cast(unsigned short, __float2bfloat16(f));
}

// ---------------------------------------------------------------------------
// One block per patch location l. 256 threads = 4 waves in 2x2:
//   wave (wr,wc) computes b in [wr*32, wr*32+32), f in [wc*64, wc*64+64)
//   via mfma_f32_16x16x32_bf16: acc[m][n], m=b-tile(2), n=f-tile(4).
// Staging: fp32 global -> regs -> bf16 -> LDS (XOR-swizzled, double-buffered).
//   x tile [64 b][64 k], w tile [128 f][64 k]; swizzle elem k ^= (row&7)<<3
//   -> ds_read_b128 fragment reads are bank-uniform (8-cycle floor).
// Epilogue: y=relu(acc+bias) -> LDS (union), fused decoder -> ws[b][l][o].
// ---------------------------------------------------------------------------
__global__ __launch_bounds__(256, 3)
void lcn_main(const float* __restrict__ x, const float* __restrict__ wgt,
              const float* __restrict__ bias, const float* __restrict__ dec_w,
              float* __restrict__ ws) {
    const int l  = blockIdx.x;
    const int hb = l >> 6, wb = l & 63;
    const int t  = threadIdx.x;
    const int lane = t & 63;
    const int wid  = t >> 6;
    const int wr   = wid >> 1;      // b-half
    const int wc   = wid & 1;       // f-half
    const int ln15 = lane & 15;
    const int kg   = lane >> 4;     // k-subgroup 0..3

    __shared__ union {
        struct { unsigned short xs[2][64 * CHUNK]; unsigned short wm[2][128 * CHUNK]; } s; // 48 KB
        float ysm[B_][132];          // 33.8 KB (after main loop)
        float red[16][B_][OUT_];     // 40 KB   (after ysm reads)
    } u;

    // ---- staging thread mappings (fully dense 64B-line global access) ----
    const int sfg = t >> 4;          // w: f-group 0..15  (f = p*16 + sfg)
    const int swk = (t & 15) * 4;    // w: k-offset; lanes 0-15 cover 256B of one f-row
    const int sxb = t >> 2;          // x: batch 0..63
    const int sxq = (t & 3) * 4;     // x: j-offset; 4 lanes cover one 64B row segment

    const float* xrow0 = x + (size_t)sxb * HW_ + (size_t)(hb * 16) * WIMG_ + wb * 16 + sxq;

    float4 wg[8], xg[4];

    auto LOADC = [&](int c) {
        #pragma unroll
        for (int p = 0; p < 8; ++p) {
            const int f = p * 16 + sfg;
            wg[p] = *reinterpret_cast<const float4*>(
                wgt + ((size_t)f * L_ + l) * K_ + c * CHUNK + swk);
        }
        #pragma unroll
        for (int i = 0; i < 4; ++i)
            xg[i] = *reinterpret_cast<const float4*>(xrow0 + (size_t)(c * 4 + i) * WIMG_);
    };
    auto WRITEC = [&](int buf) {
        #pragma unroll
        for (int p = 0; p < 8; ++p) {
            const int f = p * 16 + sfg;
            const int e = f * CHUNK + (swk ^ ((f & 7) << 3));
            ushort4 v = make_ushort4(f2bf(wg[p].x), f2bf(wg[p].y), f2bf(wg[p].z), f2bf(wg[p].w));
            *reinterpret_cast<ushort4*>(&u.s.wm[buf][e]) = v;
        }
        #pragma unroll
        for (int i = 0; i < 4; ++i) {
            const int k0 = i * 16 + sxq;
            const int e = sxb * CHUNK + (k0 ^ ((sxb & 7) << 3));
            ushort4 v = make_ushort4(f2bf(xg[i].x), f2bf(xg[i].y), f2bf(xg[i].z), f2bf(xg[i].w));
            *reinterpret_cast<ushort4*>(&u.s.xs[buf][e]) = v;
        }
    };

    f32x4 acc[2][4];
    #pragma unroll
    for (int m = 0; m < 2; ++m)
        #pragma unroll
        for (int n = 0; n < 4; ++n)
            acc[m][n] = (f32x4){0.f, 0.f, 0.f, 0.f};

    LOADC(0);
    WRITEC(0);
    LOADC(1);
    __syncthreads();

    int cur = 0;
    for (int c = 0; c < NCHUNK; ++c) {
        #pragma unroll
        for (int ks = 0; ks < 2; ++ks) {
            const int kbase = ks * 32 + kg * 8;
            bf16x8 a[2], bb[4];
            #pragma unroll
            for (int m = 0; m < 2; ++m) {
                const int b = wr * 32 + m * 16 + ln15;
                a[m] = *reinterpret_cast<const bf16x8*>(
                    &u.s.xs[cur][b * CHUNK + (kbase ^ ((b & 7) << 3))]);
            }
            #pragma unroll
            for (int n = 0; n < 4; ++n) {
                const int f = wc * 64 + n * 16 + ln15;
                bb[n] = *reinterpret_cast<const bf16x8*>(
                    &u.s.wm[cur][f * CHUNK + (kbase ^ ((f & 7) << 3))]);
            }
            #pragma unroll
            for (int m = 0; m < 2; ++m)
                #pragma unroll
                for (int n = 0; n < 4; ++n)
                    acc[m][n] = __builtin_amdgcn_mfma_f32_16x16x32_bf16(
                        a[m], bb[n], acc[m][n], 0, 0, 0);
        }
        if (c + 1 < NCHUNK) {
            WRITEC(cur ^ 1);
            if (c + 2 < NCHUNK) LOADC(c + 2);
        }
        __syncthreads();
        cur ^= 1;
    }

    // ---- epilogue: bias + ReLU, y -> LDS (staging bufs are dead; barrier passed) ----
    float bv[4];
    #pragma unroll
    for (int n = 0; n < 4; ++n)
        bv[n] = bias[(size_t)(wc * 64 + n * 16 + ln15) * L_ + l];

    #pragma unroll
    for (int m = 0; m < 2; ++m)
        #pragma unroll
        for (int n = 0; n < 4; ++n)
            #pragma unroll
            for (int r = 0; r < 4; ++r) {
                const int b = wr * 32 + m * 16 + kg * 4 + r;   // C/D: row = (lane>>4)*4+reg
                const int f = wc * 64 + n * 16 + ln15;         // C/D: col = lane&15
                u.ysm[b][f] = fmaxf(acc[m][n][r] + bv[n], 0.f);
            }
    __syncthreads();

    // ---- fused decoder (round-2 pattern): thread owns 4 b x 8 f ----
    const int tx = t & 15, ty = t >> 4;
    const int b0 = tx * 4, f0 = ty * 8;

    float yv[4][8];
    #pragma unroll
    for (int bi = 0; bi < 4; ++bi) {
        f32x4 p0 = *reinterpret_cast<const f32x4*>(&u.ysm[b0 + bi][f0]);
        f32x4 p1 = *reinterpret_cast<const f32x4*>(&u.ysm[b0 + bi][f0 + 4]);
        yv[bi][0] = p0.x; yv[bi][1] = p0.y; yv[bi][2] = p0.z; yv[bi][3] = p0.w;
        yv[bi][4] = p1.x; yv[bi][5] = p1.y; yv[bi][6] = p1.z; yv[bi][7] = p1.w;
    }
    __syncthreads();   // all ysm reads done before red overwrites the union

    float part[4][OUT_];
    #pragma unroll
    for (int bi = 0; bi < 4; ++bi)
        #pragma unroll
        for (int o = 0; o < OUT_; ++o) part[bi][o] = 0.f;

    #pragma unroll
    for (int fj = 0; fj < 8; ++fj) {
        #pragma unroll
        for (int o = 0; o < OUT_; ++o) {
            const float dw = dec_w[(size_t)o * ((size_t)F_ * L_) + (size_t)(f0 + fj) * L_ + l];
            #pragma unroll
            for (int bi = 0; bi < 4; ++bi)
                part[bi][o] = fmaf(yv[bi][fj], dw, part[bi][o]);
        }
    }

    #pragma unroll
    for (int bi = 0; bi < 4; ++bi)
        #pragma unroll
        for (int o = 0; o < OUT_; ++o)
            u.red[ty][b0 + bi][o] = part[bi][o];
    __syncthreads();

    for (int idx = t; idx < B_ * OUT_; idx += 256) {
        const int b = idx / OUT_;
        const int o = idx - b * OUT_;
        float s = 0.f;
        #pragma unroll
        for (int g = 0; g < 16; ++g) s += u.red[g][b][o];
        ws[(size_t)b * ((size_t)L_ * OUT_) + (size_t)l * OUT_ + o] = s;
    }
}

// ---------------------------------------------------------------------------
// Kernel B: reduce ws over l, add dec_b.
// ---------------------------------------------------------------------------
__global__ __launch_bounds__(640)
void lcn_reduce(const float* __restrict__ ws, const float* __restrict__ dec_b,
                float* __restrict__ out) {
    const int b = blockIdx.x;
    const int j = threadIdx.x;            // 0..639
    const float* base = ws + (size_t)b * ((size_t)L_ * OUT_);

    float s = 0.f;
    #pragma unroll 8
    for (int i = 0; i < 64; ++i)
        s += base[j + i * (64 * OUT_)];

    __shared__ float lds[64 * OUT_];
    lds[j] = s;
    __syncthreads();

    if (j < OUT_) {
        float tot = dec_b[j];
        #pragma unroll
        for (int lc = 0; lc < 64; ++lc) tot += lds[lc * OUT_ + j];
        out[b * OUT_ + j] = tot;
    }
}

extern "C" void kernel_launch(void* const* d_in, const int* in_sizes, int n_in,
                              void* d_out, int out_size, void* d_ws, size_t ws_size,
                              hipStream_t stream) {
    const float* x     = (const float*)d_in[0];
    const float* wgt   = (const float*)d_in[1];
    const float* bias  = (const float*)d_in[2];
    const float* dec_w = (const float*)d_in[3];
    const float* dec_b = (const float*)d_in[4];
    float* out = (float*)d_out;
    float* wsf = (float*)d_ws;   // 64*4096*10*4 = 10.49 MB

    lcn_main<<<dim3(L_), dim3(256), 0, stream>>>(x, wgt, bias, dec_w, wsf);
    lcn_reduce<<<dim3(B_), dim3(640), 0, stream>>>(wsf, dec_b, out);
}

// Round 4
// 267.802 us; speedup vs baseline: 3.9033x; 1.0236x over previous
//
#include <hip/hip_runtime.h>
#include <hip/hip_bf16.h>

// B=64, C=1, H=W=1024, KS=16, F=128, OUT=10, L=4096, K=256
#define B_    64
#define F_    128
#define L_    4096
#define K_    256
#define OUT_  10
#define HW_   (1024 * 1024)
#define WIMG_ 1024

typedef __attribute__((ext_vector_type(8))) short bf16x8;   // MFMA A/B frag
typedef __attribute__((ext_vector_type(4))) float f32x4;    // MFMA C/D frag

static __device__ __forceinline__ unsigned short f2bf(float f) {
    return __builtin_bit_cast(unsigned short, __float2bfloat16(f));
}
static __device__ __forceinline__ bf16x8 cvt8(float4 a, float4 b) {
    bf16x8 r;
    r[0] = (short)f2bf(a.x); r[1] = (short)f2bf(a.y);
    r[2] = (short)f2bf(a.z); r[3] = (short)f2bf(a.w);
    r[4] = (short)f2bf(b.x); r[5] = (short)f2bf(b.y);
    r[6] = (short)f2bf(b.z); r[7] = (short)f2bf(b.w);
    return r;
}

// ---------------------------------------------------------------------------
// One block per patch location l. 4 waves; wave wc owns f in [wc*32, wc*32+32).
//   acc[m][n]: m = b-tile (4 x 16), n = f-tile (2 x 16)  (mfma 16x16x32 bf16)
// w path: global -> regs -> bf16 -> MFMA B-frag DIRECTLY (layout matches!).
//   No LDS, no barriers, no redundancy (waves own disjoint f). 512 MB stream.
// x path: whole 64b x 256k tile staged to LDS bf16 (swizzled) once; ONE barrier.
// Epilogue: y -> LDS (union), fused decoder, per-l partials -> ws[b][l][o].
// ---------------------------------------------------------------------------
__global__ __launch_bounds__(256, 3)
void lcn_main(const float* __restrict__ x, const float* __restrict__ wgt,
              const float* __restrict__ bias, const float* __restrict__ dec_w,
              float* __restrict__ ws) {
    const int l  = blockIdx.x;
    const int hb = l >> 6, wb = l & 63;
    const int t  = threadIdx.x;
    const int lane = t & 63;
    const int wc   = t >> 6;        // wave id = f-quarter
    const int ln15 = lane & 15;
    const int kg   = lane >> 4;     // k-subgroup 0..3

    __shared__ union {
        unsigned short xs[B_ * K_];  // 32 KB bf16, swizzled (k ^= (b&7)<<3)
        float ysm[B_][132];          // 33.8 KB (after main loop)
        float red[16][B_][OUT_];     // 40 KB   (after ysm reads)
    } u;

    // ---- stage x: thread handles b = t>>2, cols j0 = (t&3)*4, all 16 rows ----
    {
        const int b  = t >> 2;
        const int j0 = (t & 3) * 4;
        const float* xp = x + (size_t)b * HW_ + (size_t)(hb * 16) * WIMG_ + wb * 16 + j0;
        float4 v[16];
        #pragma unroll
        for (int r = 0; r < 16; ++r)
            v[r] = *reinterpret_cast<const float4*>(xp + (size_t)r * WIMG_);
        const int swz = (b & 7) << 3;
        #pragma unroll
        for (int r = 0; r < 16; ++r) {
            const int k = r * 16 + j0;
            ushort4 s4 = make_ushort4(f2bf(v[r].x), f2bf(v[r].y), f2bf(v[r].z), f2bf(v[r].w));
            *reinterpret_cast<ushort4*>(&u.xs[b * K_ + (k ^ swz)]) = s4;
        }
    }
    __syncthreads();   // the ONLY barrier before the epilogue

    // ---- main loop: stream w from global, A-frags from LDS, 64 MFMAs ----
    const float* w0p = wgt + ((size_t)(wc * 32 + ln15) * L_ + l) * K_;      // n=0 row
    const float* w1p = w0p + (size_t)16 * L_ * K_;                          // n=1 row

    f32x4 acc[4][2];
    #pragma unroll
    for (int m = 0; m < 4; ++m)
        #pragma unroll
        for (int n = 0; n < 2; ++n)
            acc[m][n] = (f32x4){0.f, 0.f, 0.f, 0.f};

    #pragma unroll
    for (int ks = 0; ks < 8; ++ks) {
        const int kb = ks * 32 + kg * 8;
        const float4 wa0 = *reinterpret_cast<const float4*>(w0p + kb);
        const float4 wa1 = *reinterpret_cast<const float4*>(w0p + kb + 4);
        const float4 wb0 = *reinterpret_cast<const float4*>(w1p + kb);
        const float4 wb1 = *reinterpret_cast<const float4*>(w1p + kb + 4);
        const bf16x8 b0 = cvt8(wa0, wa1);
        const bf16x8 b1 = cvt8(wb0, wb1);
        bf16x8 a[4];
        #pragma unroll
        for (int m = 0; m < 4; ++m) {
            const int b = m * 16 + ln15;
            a[m] = *reinterpret_cast<const bf16x8*>(
                &u.xs[b * K_ + (kb ^ ((b & 7) << 3))]);
        }
        #pragma unroll
        for (int m = 0; m < 4; ++m) {
            acc[m][0] = __builtin_amdgcn_mfma_f32_16x16x32_bf16(a[m], b0, acc[m][0], 0, 0, 0);
            acc[m][1] = __builtin_amdgcn_mfma_f32_16x16x32_bf16(a[m], b1, acc[m][1], 0, 0, 0);
        }
    }

    // ---- epilogue: bias + ReLU -> ysm (union; sync xs readers first) ----
    float bv[2];
    #pragma unroll
    for (int n = 0; n < 2; ++n)
        bv[n] = bias[(size_t)(wc * 32 + n * 16 + ln15) * L_ + l];

    __syncthreads();   // all waves done reading xs before ysm overwrites it

    #pragma unroll
    for (int m = 0; m < 4; ++m)
        #pragma unroll
        for (int n = 0; n < 2; ++n)
            #pragma unroll
            for (int r = 0; r < 4; ++r) {
                const int b = m * 16 + kg * 4 + r;       // C/D: row = (lane>>4)*4+reg
                const int f = wc * 32 + n * 16 + ln15;   // C/D: col = lane&15
                u.ysm[b][f] = fmaxf(acc[m][n][r] + bv[n], 0.f);
            }
    __syncthreads();

    // ---- fused decoder: thread owns 4 b x 8 f ----
    const int tx = t & 15, ty = t >> 4;
    const int b0_ = tx * 4, f0_ = ty * 8;

    float yv[4][8];
    #pragma unroll
    for (int bi = 0; bi < 4; ++bi) {
        f32x4 p0 = *reinterpret_cast<const f32x4*>(&u.ysm[b0_ + bi][f0_]);
        f32x4 p1 = *reinterpret_cast<const f32x4*>(&u.ysm[b0_ + bi][f0_ + 4]);
        yv[bi][0] = p0.x; yv[bi][1] = p0.y; yv[bi][2] = p0.z; yv[bi][3] = p0.w;
        yv[bi][4] = p1.x; yv[bi][5] = p1.y; yv[bi][6] = p1.z; yv[bi][7] = p1.w;
    }
    __syncthreads();   // ysm reads done before red overwrites the union

    float part[4][OUT_];
    #pragma unroll
    for (int bi = 0; bi < 4; ++bi)
        #pragma unroll
        for (int o = 0; o < OUT_; ++o) part[bi][o] = 0.f;

    #pragma unroll
    for (int fj = 0; fj < 8; ++fj) {
        #pragma unroll
        for (int o = 0; o < OUT_; ++o) {
            const float dw = dec_w[(size_t)o * ((size_t)F_ * L_) + (size_t)(f0_ + fj) * L_ + l];
            #pragma unroll
            for (int bi = 0; bi < 4; ++bi)
                part[bi][o] = fmaf(yv[bi][fj], dw, part[bi][o]);
        }
    }

    #pragma unroll
    for (int bi = 0; bi < 4; ++bi)
        #pragma unroll
        for (int o = 0; o < OUT_; ++o)
            u.red[ty][b0_ + bi][o] = part[bi][o];
    __syncthreads();

    for (int idx = t; idx < B_ * OUT_; idx += 256) {
        const int b = idx / OUT_;
        const int o = idx - b * OUT_;
        float s = 0.f;
        #pragma unroll
        for (int g = 0; g < 16; ++g) s += u.red[g][b][o];
        ws[(size_t)b * ((size_t)L_ * OUT_) + (size_t)l * OUT_ + o] = s;
    }
}

// ---------------------------------------------------------------------------
// Kernel B: reduce ws over l, add dec_b.
// ---------------------------------------------------------------------------
__global__ __launch_bounds__(640)
void lcn_reduce(const float* __restrict__ ws, const float* __restrict__ dec_b,
                float* __restrict__ out) {
    const int b = blockIdx.x;
    const int j = threadIdx.x;            // 0..639
    const float* base = ws + (size_t)b * ((size_t)L_ * OUT_);

    float s = 0.f;
    #pragma unroll 8
    for (int i = 0; i < 64; ++i)
        s += base[j + i * (64 * OUT_)];

    __shared__ float lds[64 * OUT_];
    lds[j] = s;
    __syncthreads();

    if (j < OUT_) {
        float tot = dec_b[j];
        #pragma unroll
        for (int lc = 0; lc < 64; ++lc) tot += lds[lc * OUT_ + j];
        out[b * OUT_ + j] = tot;
    }
}

extern "C" void kernel_launch(void* const* d_in, const int* in_sizes, int n_in,
                              void* d_out, int out_size, void* d_ws, size_t ws_size,
                              hipStream_t stream) {
    const float* x     = (const float*)d_in[0];
    const float* wgt   = (const float*)d_in[1];
    const float* bias  = (const float*)d_in[2];
    const float* dec_w = (const float*)d_in[3];
    const float* dec_b = (const float*)d_in[4];
    float* out = (float*)d_out;
    float* wsf = (float*)d_ws;   // 64*4096*10*4 = 10.49 MB

    lcn_main<<<dim3(L_), dim3(256), 0, stream>>>(x, wgt, bias, dec_w, wsf);
    lcn_reduce<<<dim3(B_), dim3(640), 0, stream>>>(wsf, dec_b, out);
}